// Round 11
// baseline (410.257 us; speedup 1.0000x reference)
//
#include <hip/hip_runtime.h>
#include <hip/hip_bf16.h>
#include <math.h>

typedef __bf16 bf16;
typedef __attribute__((ext_vector_type(8))) __bf16 bf16x8;
typedef __attribute__((ext_vector_type(4))) __bf16 bf16x4;
typedef __attribute__((ext_vector_type(4))) float f32x4;

#define DEVI static __device__ __forceinline__

// byte offset of 16B chunk within a 128B LDS row, XOR-swizzled
DEVI int swzb(int row, int ch) { return ((ch ^ (row & 7)) << 4); }

// async global->LDS 16B: per-lane global src, wave-uniform LDS base (+lane*16 by HW)
DEVI void gl_lds16(const void* g, void* l) {
  __builtin_amdgcn_global_load_lds(
      (const __attribute__((address_space(1))) unsigned int*)g,
      (__attribute__((address_space(3))) unsigned int*)l, 16, 0, 0);
}

template<int N> DEVI void wait_vm() {
  if constexpr (N == 0) asm volatile("s_waitcnt vmcnt(0)" ::: "memory");
  else if constexpr (N == 4) asm volatile("s_waitcnt vmcnt(4)" ::: "memory");
  else if constexpr (N == 6) asm volatile("s_waitcnt vmcnt(6)" ::: "memory");
  else if constexpr (N == 8) asm volatile("s_waitcnt vmcnt(8)" ::: "memory");
}
DEVI void sbar() {
  __builtin_amdgcn_sched_barrier(0);
  __builtin_amdgcn_s_barrier();
  __builtin_amdgcn_sched_barrier(0);
}

// ---------------------------------------------------------------------------
// prep: weights -> bf16 (wqk = concat(wpq,wpk); wcvT = wcv transposed), bqk
// ---------------------------------------------------------------------------
__global__ __launch_bounds__(256) void prep_weights(
    const float* __restrict__ wpq, const float* __restrict__ wpk,
    const float* __restrict__ wpv, const float* __restrict__ wcq,
    const float* __restrict__ wck, const float* __restrict__ wcv,
    const float* __restrict__ bpq, const float* __restrict__ bpk,
    bf16* __restrict__ wqk, bf16* __restrict__ wpvb, bf16* __restrict__ wcqb,
    bf16* __restrict__ wckb, bf16* __restrict__ wcvT, float* __restrict__ bqk)
{
  int i = blockIdx.x * 256 + threadIdx.x;
  switch (blockIdx.y) {
    case 0: if (i < 64*512)  wqk[i]          = (bf16)wpq[i]; break;
    case 1: if (i < 64*512)  wqk[64*512 + i] = (bf16)wpk[i]; break;
    case 2: if (i < 512*512) wpvb[i] = (bf16)wpv[i]; break;
    case 3: if (i < 512*512) wcqb[i] = (bf16)wcq[i]; break;
    case 4: if (i < 512*512) wckb[i] = (bf16)wck[i]; break;
    case 5: if (i < 512*512) { int t = i >> 9, j = i & 511; wcvT[i] = (bf16)wcv[j*512 + t]; } break;
    case 6: if (i < 64) bqk[i] = bpq[i]; else if (i < 128) bqk[i] = bpk[i - 64]; break;
  }
}

// ---------------------------------------------------------------------------
// x (B,512,4096) fp32 -> xbT (B,4096,512) bf16
// ---------------------------------------------------------------------------
__global__ __launch_bounds__(256) void transpose_x(const float* __restrict__ x, bf16* __restrict__ xbT)
{
  __shared__ float t[32][33];
  int b = blockIdx.z, n0 = blockIdx.x * 32, c0 = blockIdx.y * 32;
  int tx = threadIdx.x & 31, ty = threadIdx.x >> 5;
#pragma unroll
  for (int i = 0; i < 4; ++i)
    t[ty + 8*i][tx] = x[((size_t)b*512 + c0 + ty + 8*i)*4096 + n0 + tx];
  __syncthreads();
#pragma unroll
  for (int i = 0; i < 4; ++i)
    xbT[((size_t)b*4096 + n0 + ty + 8*i)*512 + c0 + tx] = (bf16)t[tx][ty + 8*i];
}

// ---------------------------------------------------------------------------
// generic bf16 MFMA GEMM. C[m,n] = sum_k A[m,k]*Bt[n,k]  (+bias/epilogues)
// (BM+BN)<=192: triple-buffered, raw barrier + counted vmcnt. Else 2-buf sync.
// BIAS: 0 none, 1 +biasM[m], 2 +biasN[n]
// EPI : 0 bf16 store, 1 f32 store, 2 f32 + rank1 bias terms (L), 3 final out
// remap=1: flat grid (512), batch pinned to XCD pair (assumes phys%8 = XCD)
// ---------------------------------------------------------------------------
struct GemmP {
  const bf16* A; const bf16* Bt; void* C;
  long aS, bS;       // batch strides (elements)
  long cSbytes;      // batch stride of C in bytes
  int lda, ldb, ldc, K;
  int remap;
  const float* biasM; const float* biasN;
  const float* e_bq; const float* e_v; const float* e_u; const float* e_bk; float e_nn;
  long vS, uS;
  const float* gchan; const float* Abv; const bf16* Pres; long abvS, presS;
};

template<int BM, int BN, int BIAS, int EPI>
__global__ __launch_bounds__(256) void gemm_k(GemmP p)
{
  constexpr int QF = BM / 32;
  constexpr int CF = BN / 32;
  constexpr int NBUF = (BM + BN <= 192) ? 3 : 2;
  constexpr int LOADS = (BM + BN) / 32;   // gl_lds per wave per stage
  __shared__ __align__(16) char sa[NBUF][BM * 128];
  __shared__ __align__(16) char sb[NBUF][BN * 128];
  const int tid = threadIdx.x, lane = tid & 63, w = tid >> 6;
  const int g = lane >> 4, l15 = lane & 15;
  int bx = blockIdx.x, by = blockIdx.y, bz = blockIdx.z;
  if (p.remap) {  // grid (4,32,4) flattened to 512; batch -> XCD pair
    int ph = blockIdx.x;
    bz = (ph & 7) >> 1;
    int idx = ((ph & 1) << 6) | (ph >> 3);  // [0,128)
    bx = idx & 3; by = idx >> 2;
  }
  const int bm = bx * BM, bn = by * BN;
  const bf16* A  = p.A  + (size_t)bz * p.aS;
  const bf16* Bt = p.Bt + (size_t)bz * p.bS;
  char* Cb = (char*)p.C + (size_t)bz * p.cSbytes;
  const int wm = (w & 1) * (BM / 2), wn = (w >> 1) * (BN / 2);
  const int srow = tid >> 3, sch = tid & 7;

  f32x4 acc[QF][CF];
#pragma unroll
  for (int i = 0; i < QF; ++i)
#pragma unroll
    for (int j = 0; j < CF; ++j) acc[i][j] = f32x4{0.f, 0.f, 0.f, 0.f};

  auto stage = [&](int k0, int bi) {
#pragma unroll
    for (int it = 0; it < BM / 32; ++it) {
      int r = it * 32 + srow;
      gl_lds16(A + (size_t)(bm + r) * p.lda + k0 + ((sch ^ (r & 7)) * 8),
               sa[bi] + (it * 32 + w * 8) * 128);
    }
#pragma unroll
    for (int it = 0; it < BN / 32; ++it) {
      int r = it * 32 + srow;
      gl_lds16(Bt + (size_t)(bn + r) * p.ldb + k0 + ((sch ^ (r & 7)) * 8),
               sb[bi] + (it * 32 + w * 8) * 128);
    }
  };
  auto compute = [&](int bi) {
#pragma unroll
    for (int kc = 0; kc < 2; ++kc) {
      bf16x8 af[QF], bfr[CF];
#pragma unroll
      for (int qf = 0; qf < QF; ++qf) {
        int row = wm + 16 * qf + l15;
        af[qf] = *(const bf16x8*)(sa[bi] + row * 128 + swzb(row, g + 4 * kc));
      }
#pragma unroll
      for (int cf = 0; cf < CF; ++cf) {
        int row = wn + 16 * cf + l15;
        bfr[cf] = *(const bf16x8*)(sb[bi] + row * 128 + swzb(row, g + 4 * kc));
      }
      __builtin_amdgcn_s_setprio(1);
#pragma unroll
      for (int qf = 0; qf < QF; ++qf)
#pragma unroll
        for (int cf = 0; cf < CF; ++cf)
          acc[qf][cf] = __builtin_amdgcn_mfma_f32_16x16x32_bf16(af[qf], bfr[cf], acc[qf][cf], 0, 0, 0);
      __builtin_amdgcn_s_setprio(0);
    }
  };

  const int nk = p.K >> 6;
  if constexpr (NBUF == 3) {
    stage(0, 0);
    if (nk > 1) { stage(64, 1); wait_vm<LOADS>(); } else wait_vm<0>();
    sbar();
    int bi = 0;
    for (int t = 0; t < nk; ++t) {
      int b2 = bi + 2; if (b2 >= 3) b2 -= 3;
      if (t + 2 < nk) stage((t + 2) << 6, b2);
      compute(bi);
      if (t + 1 < nk) {
        if (t + 2 < nk) wait_vm<LOADS>(); else wait_vm<0>();
        sbar();
      }
      if (++bi == 3) bi = 0;
    }
  } else {
    stage(0, 0);
    __syncthreads();
    for (int t = 0; t < nk; ++t) {
      const int cur = t & 1;
      if (t + 1 < nk) stage((t + 1) << 6, cur ^ 1);
      compute(cur);
      __syncthreads();
    }
  }

  // epilogue
  float gc = 0.f;
  const float* AbvB = nullptr; const bf16* PresB = nullptr;
  const float* eV = nullptr; const float* eU = nullptr;
  if (EPI == 3) { gc = p.gchan[0]; AbvB = p.Abv + (size_t)bz * p.abvS; PresB = p.Pres + (size_t)bz * p.presS; }
  if (EPI == 2) { eV = p.e_v + (size_t)bz * p.vS; eU = p.e_u + (size_t)bz * p.uS; }

#pragma unroll
  for (int qf = 0; qf < QF; ++qf)
#pragma unroll
    for (int cf = 0; cf < CF; ++cf)
#pragma unroll
      for (int r = 0; r < 4; ++r) {
        int m = bm + wm + 16 * qf + 4 * g + r;
        int n = bn + wn + 16 * cf + l15;
        float v = acc[qf][cf][r];
        if (BIAS == 1) v += p.biasM[m];
        if (BIAS == 2) v += p.biasN[n];
        size_t idx = (size_t)m * p.ldc + n;
        if (EPI == 0) ((bf16*)Cb)[idx] = (bf16)v;
        else if (EPI == 1) ((float*)Cb)[idx] = v;
        else if (EPI == 2) {
          v += p.e_bq[m] * eV[n] + eU[m] * p.e_bk[n] + p.e_nn * p.e_bq[m] * p.e_bk[n];
          ((float*)Cb)[idx] = v;
        } else {
          v = gc * (v + AbvB[m]) + (float)PresB[idx];
          ((float*)Cb)[idx] = v;
        }
      }
}

// ---------------------------------------------------------------------------
// flash position attention (r7 champion schedule) + fused row-sum epilogue.
//  - c-split: 64q x 256c per block, grid 512 = 2 blocks/CU
//  - K dbuf gl_lds; V staged via gl_lds issued after barrier2, retired at
//    barrier1 (vmcnt(1): K stays airborne); 2 barriers/iter
//  - epilogue: Pb, PTb writes + per-block partial row sums atomicAdd -> rws
// LDS: K0@0 K1@8K V@16K P@48K lsum@56K; epilogue Och reuse [0,34816)
// ---------------------------------------------------------------------------
__global__ __launch_bounds__(512, 4) void flash_pos(
    const bf16* __restrict__ QKT, const bf16* __restrict__ Vv,
    const float* __restrict__ x, const float* __restrict__ gpos,
    bf16* __restrict__ Pb, bf16* __restrict__ PTb, float* __restrict__ rws)
{
  extern __shared__ char sm[];
  char* Vlds = sm + 16384;
  char* Plds = sm + 49152;
  float* Och  = (float*)sm;
  float* lsum = (float*)(sm + 57344);

  const int tid = threadIdx.x, lane = tid & 63, w = tid >> 6;
  const int g = lane >> 4, l15 = lane & 15;
  const int wq = w & 3;                  // q-row group (rows 16wq..16wq+15)
  const int wh = w >> 2;                 // kv col half (cols 32wh..32wh+31)
  const int phys = blockIdx.x;
  const int b  = (phys & 7) >> 1;
  const int ch = phys & 1;
  const int q0 = (phys >> 3) << 6;
  const int c0 = ch << 8;

  const bf16* QKTb = QKT + (size_t)b * 4096 * 128;
  const bf16* Vb   = Vv  + (size_t)b * 512 * 4096;

  const bf16* qrow = QKTb + (size_t)(q0 + 16 * wq + l15) * 128;
  bf16x8 qa0 = *(const bf16x8*)(qrow + 8 * g);
  bf16x8 qa1 = *(const bf16x8*)(qrow + 32 + 8 * g);

  f32x4 acc[4][2];
#pragma unroll
  for (int i = 0; i < 4; ++i) { acc[i][0] = f32x4{0.f,0.f,0.f,0.f}; acc[i][1] = f32x4{0.f,0.f,0.f,0.f}; }
  f32x4 l_r = f32x4{0.f, 0.f, 0.f, 0.f};

  const int srow = tid >> 3, sch = tid & 7;
  const bf16* Ksrc = QKTb + (size_t)srow * 128 + 64 + ((sch ^ (srow & 7)) * 8); // + kt*8192

  // prologue: stage K(0) + V(0)
  gl_lds16(Ksrc, sm + w * 1024);
#pragma unroll
  for (int it = 0; it < 4; ++it) {
    int r = it * 64 + srow;
    gl_lds16(Vb + (size_t)(c0 + r) * 4096 + ((sch ^ (r & 7)) * 8),
             Vlds + (it * 64 + w * 8) * 128);
  }
  asm volatile("s_waitcnt vmcnt(0)" ::: "memory");
  sbar();

  for (int t = 0; t < 64; ++t) {
    const char* Kcur = sm + ((t & 1) << 13);
    char* Knext = sm + (((t + 1) & 1) << 13);
    const int ktn = (t + 1) & 63;
    // ---- phase A: stage K(t+1); QK(t); exp; P write ----
    gl_lds16(Ksrc + (size_t)ktn * 8192, Knext + w * 1024);
    __builtin_amdgcn_sched_barrier(0);
    f32x4 s0 = f32x4{0.f,0.f,0.f,0.f}, s1 = f32x4{0.f,0.f,0.f,0.f};
    {
      const int r0 = 32 * wh + l15, r1 = r0 + 16;
      bf16x8 k00 = *(const bf16x8*)(Kcur + r0 * 128 + swzb(r0, g));
      bf16x8 k01 = *(const bf16x8*)(Kcur + r0 * 128 + swzb(r0, g + 4));
      bf16x8 k10 = *(const bf16x8*)(Kcur + r1 * 128 + swzb(r1, g));
      bf16x8 k11 = *(const bf16x8*)(Kcur + r1 * 128 + swzb(r1, g + 4));
      __builtin_amdgcn_s_setprio(1);
      s0 = __builtin_amdgcn_mfma_f32_16x16x32_bf16(qa0, k00, s0, 0, 0, 0);
      s0 = __builtin_amdgcn_mfma_f32_16x16x32_bf16(qa1, k01, s0, 0, 0, 0);
      s1 = __builtin_amdgcn_mfma_f32_16x16x32_bf16(qa0, k10, s1, 0, 0, 0);
      s1 = __builtin_amdgcn_mfma_f32_16x16x32_bf16(qa1, k11, s1, 0, 0, 0);
      __builtin_amdgcn_s_setprio(0);
    }
#pragma unroll
    for (int r = 0; r < 4; ++r) {
      float e0 = __expf(s0[r]), e1 = __expf(s1[r]);
      l_r[r] += e0 + e1;
      int row = 16 * wq + 4 * g + r;
      int ca = 32 * wh + l15, cb = ca + 16;
      *(bf16*)(Plds + row * 128 + (((ca >> 3) ^ (row & 7)) << 4) + ((ca & 7) * 2)) = (bf16)e0;
      *(bf16*)(Plds + row * 128 + (((cb >> 3) ^ (row & 7)) << 4) + ((cb & 7) * 2)) = (bf16)e1;
    }
    // barrier1: P(t) visible; V(t) landed (vmcnt(1): K(t+1) stays airborne)
    asm volatile("s_waitcnt vmcnt(1) lgkmcnt(0)" ::: "memory");
    sbar();
    // ---- phase B: PV(t) from LDS ----
    __builtin_amdgcn_s_setprio(1);
#pragma unroll
    for (int kc = 0; kc < 2; ++kc) {
      const int vra = 32 * w + l15, vrb = vra + 16;
      bf16x8 v0 = *(const bf16x8*)(Vlds + vra * 128 + swzb(vra, g + 4 * kc));
      bf16x8 v1 = *(const bf16x8*)(Vlds + vrb * 128 + swzb(vrb, g + 4 * kc));
#pragma unroll
      for (int qf = 0; qf < 4; ++qf) {
        int row = 16 * qf + l15;
        bf16x8 ap = *(const bf16x8*)(Plds + row * 128 + swzb(row, g + 4 * kc));
        acc[qf][0] = __builtin_amdgcn_mfma_f32_16x16x32_bf16(ap, v0, acc[qf][0], 0, 0, 0);
        acc[qf][1] = __builtin_amdgcn_mfma_f32_16x16x32_bf16(ap, v1, acc[qf][1], 0, 0, 0);
      }
    }
    __builtin_amdgcn_s_setprio(0);
    // barrier2: K(t+1) landed, all PV LDS reads done -> V/P safe to overwrite
    asm volatile("s_waitcnt vmcnt(0) lgkmcnt(0)" ::: "memory");
    sbar();
    // stage V(t+1) (retired at barrier1 of t+1 via vmcnt(1))
#pragma unroll
    for (int it = 0; it < 4; ++it) {
      int r = it * 64 + srow;
      gl_lds16(Vb + (size_t)(c0 + r) * 4096 + ktn * 64 + ((sch ^ (r & 7)) * 8),
               Vlds + (it * 64 + w * 8) * 128);
    }
  }
  // drain wrap prefetch before LDS reuse as Och
  asm volatile("s_waitcnt vmcnt(0) lgkmcnt(0)" ::: "memory");
  sbar();

  // reduce l over the 16 lanes of each group (covers this wave's 32 cols)
#pragma unroll
  for (int off = 1; off < 16; off <<= 1) {
#pragma unroll
    for (int r = 0; r < 4; ++r) l_r[r] += __shfl_xor(l_r[r], off);
  }
  if (l15 == 0)
#pragma unroll
    for (int r = 0; r < 4; ++r) lsum[wh * 64 + 16 * wq + 4 * g + r] = l_r[r];
  __syncthreads();

  const float gp = gpos[0];
  for (int j = 0; j < 2; ++j) { // c chunks of 128 within this block's 256
    if ((w >> 2) == j) {
#pragma unroll
      for (int qf = 0; qf < 4; ++qf) {
        float inv[4];
#pragma unroll
        for (int r = 0; r < 4; ++r) {
          int qi = 16 * qf + 4 * g + r;
          inv[r] = gp / (lsum[qi] + lsum[64 + qi]);
        }
#pragma unroll
        for (int cf = 0; cf < 2; ++cf) {
          int cl = 32 * (w & 3) + 16 * cf + l15;
#pragma unroll
          for (int r = 0; r < 4; ++r)
            Och[cl * 68 + 16 * qf + 4 * g + r] = acc[qf][cf][r] * inv[r];
        }
      }
    }
    __syncthreads();
    { // pass1: residual add + Pb write (rows c) + partial row-sum atomicAdd
      int cl = tid >> 2, qs = (tid & 3) * 16;
      int cg = c0 + 128 * j + cl;
      const float* xr = x + ((size_t)b * 512 + cg) * 4096 + q0 + qs;
      float* och = Och + cl * 68 + qs;
      float tmp[16];
      float s16 = 0.f;
#pragma unroll
      for (int i = 0; i < 16; ++i) { tmp[i] = och[i] + xr[i]; och[i] = tmp[i]; s16 += tmp[i]; }
      bf16x8 o0, o1;
#pragma unroll
      for (int i = 0; i < 8; ++i) { o0[i] = (bf16)tmp[i]; o1[i] = (bf16)tmp[i + 8]; }
      bf16* pr = Pb + ((size_t)b * 512 + cg) * 4096 + q0 + qs;
      *(bf16x8*)pr = o0; *(bf16x8*)(pr + 8) = o1;
      atomicAdd(rws + b * 512 + cg, s16);
    }
    __syncthreads();
    { // pass2: PT write (rows q)
      int q = tid >> 3, cs = (tid & 7) * 16;
      float tmp[16];
#pragma unroll
      for (int i = 0; i < 16; ++i) tmp[i] = Och[(cs + i) * 68 + q];
      bf16x8 o0, o1;
#pragma unroll
      for (int i = 0; i < 8; ++i) { o0[i] = (bf16)tmp[i]; o1[i] = (bf16)tmp[i + 8]; }
      bf16* pt = PTb + ((size_t)b * 4096 + q0 + q) * 512 + c0 + 128 * j + cs;
      *(bf16x8*)pt = o0; *(bf16x8*)(pt + 8) = o1;
    }
    __syncthreads();
  }
}

// u = Wcq*r, v = Wck*r  (fp32)
__global__ __launch_bounds__(256) void uv_kernel(
    const float* __restrict__ wcq, const float* __restrict__ wck,
    const float* __restrict__ r, float* __restrict__ u, float* __restrict__ v)
{
  int b = blockIdx.z;
  int i = blockIdx.x * 256 + threadIdx.x;
  const float* rb = r + b * 512;
  const float* wrow = (blockIdx.y ? wck : wcq) + (size_t)i * 512;
  float s = 0.f;
  for (int t = 0; t < 512; ++t) s += wrow[t] * rb[t];
  (blockIdx.y ? v : u)[b * 512 + i] = s;
}

// softmax over rows of L (512 wide) -> Ab bf16 ; Abv[i] = sum_j A[i,j]*bcv[j]
__global__ __launch_bounds__(256) void softmax_chan(
    const float* __restrict__ L, const float* __restrict__ bcv,
    bf16* __restrict__ Ab, float* __restrict__ Abv)
{
  int b = blockIdx.z;
  int i = blockIdx.x * 4 + (threadIdx.x >> 6);
  int lane = threadIdx.x & 63;
  const float* row = L + ((size_t)b * 512 + i) * 512;
  f32x4 v0 = ((const f32x4*)row)[lane];
  f32x4 v1 = ((const f32x4*)row)[lane + 64];
  float mx = fmaxf(fmaxf(fmaxf(v0[0], v0[1]), fmaxf(v0[2], v0[3])),
                   fmaxf(fmaxf(v1[0], v1[1]), fmaxf(v1[2], v1[3])));
#pragma unroll
  for (int off = 1; off < 64; off <<= 1) mx = fmaxf(mx, __shfl_xor(mx, off));
  float e[8]; float s = 0.f;
#pragma unroll
  for (int k = 0; k < 4; ++k) { e[k] = __expf(v0[k] - mx); s += e[k]; }
#pragma unroll
  for (int k = 0; k < 4; ++k) { e[4 + k] = __expf(v1[k] - mx); s += e[4 + k]; }
#pragma unroll
  for (int off = 1; off < 64; off <<= 1) s += __shfl_xor(s, off);
  float inv = 1.f / s;
  bf16x4 a0, a1;
  const f32x4 bv0 = ((const f32x4*)bcv)[lane];
  const f32x4 bv1 = ((const f32x4*)bcv)[lane + 64];
  float pb = 0.f;
#pragma unroll
  for (int k = 0; k < 4; ++k) {
    float p0 = e[k] * inv, p1 = e[4 + k] * inv;
    a0[k] = (bf16)p0; a1[k] = (bf16)p1;
    pb += p0 * bv0[k] + p1 * bv1[k];
  }
  bf16* arow = Ab + ((size_t)b * 512 + i) * 512;
  *(bf16x4*)(arow + 4 * lane) = a0;
  *(bf16x4*)(arow + 256 + 4 * lane) = a1;
#pragma unroll
  for (int off = 1; off < 64; off <<= 1) pb += __shfl_xor(pb, off);
  if (lane == 0) Abv[b * 512 + i] = pb;
}

// ---------------------------------------------------------------------------
extern "C" void kernel_launch(void* const* d_in, const int* in_sizes, int n_in,
                              void* d_out, int out_size, void* d_ws, size_t ws_size,
                              hipStream_t stream)
{
  const float* x    = (const float*)d_in[0];
  const float* wpq  = (const float*)d_in[1];
  const float* bpq  = (const float*)d_in[2];
  const float* wpk  = (const float*)d_in[3];
  const float* bpk  = (const float*)d_in[4];
  const float* wpv  = (const float*)d_in[5];
  const float* bpv  = (const float*)d_in[6];
  const float* wcq  = (const float*)d_in[7];
  const float* bcq  = (const float*)d_in[8];
  const float* wck  = (const float*)d_in[9];
  const float* bck  = (const float*)d_in[10];
  const float* wcv  = (const float*)d_in[11];
  const float* bcv  = (const float*)d_in[12];
  const float* gpos = (const float*)d_in[13];
  const float* gch  = (const float*)d_in[14];
  float* out = (float*)d_out;

  char* ws = (char*)d_ws;
  size_t off = 0;
  auto alloc = [&](size_t bytes) -> char* {
    char* p = ws + off; off = (off + bytes + 255) & ~(size_t)255; return p;
  };
  bf16*  xbT  = (bf16*)alloc(4UL * 4096 * 512 * 2);
  bf16*  QKT  = (bf16*)alloc(4UL * 4096 * 128 * 2);
  bf16*  V    = (bf16*)alloc(4UL * 512 * 4096 * 2);
  bf16*  Pb   = (bf16*)alloc(4UL * 512 * 4096 * 2);
  bf16*  PTb  = (bf16*)alloc(4UL * 4096 * 512 * 2);
  bf16*  G    = (bf16*)alloc(4UL * 512 * 512 * 2);
  bf16*  M1   = (bf16*)alloc(4UL * 512 * 512 * 2);
  float* Lws  = (float*)alloc(4UL * 512 * 512 * 4);
  bf16*  Ab   = (bf16*)alloc(4UL * 512 * 512 * 2);
  bf16*  B2   = (bf16*)alloc(4UL * 512 * 512 * 2);
  bf16*  wqk  = (bf16*)alloc(128UL * 512 * 2);
  bf16*  wpvb = (bf16*)alloc(512UL * 512 * 2);
  bf16*  wcqb = (bf16*)alloc(512UL * 512 * 2);
  bf16*  wckb = (bf16*)alloc(512UL * 512 * 2);
  bf16*  wcvT = (bf16*)alloc(512UL * 512 * 2);
  float* bqk  = (float*)alloc(128 * 4);
  float* rws  = (float*)alloc(4UL * 512 * 4);
  float* uws  = (float*)alloc(4UL * 512 * 4);
  float* vws  = (float*)alloc(4UL * 512 * 4);
  float* Abv  = (float*)alloc(4UL * 512 * 4);
  if (off > ws_size) return;  // workspace too small: bail (bench will flag)

  prep_weights<<<dim3(1024, 7, 1), 256, 0, stream>>>(wpq, wpk, wpv, wcq, wck, wcv,
                                                     bpq, bpk, wqk, wpvb, wcqb, wckb, wcvT, bqk);
  transpose_x<<<dim3(128, 16, 4), 256, 0, stream>>>(x, xbT);
  (void)hipMemsetAsync(rws, 0, 4UL * 512 * 4, stream);

  GemmP p{};
  // QKT = xbT * wqk^T + bqk   (M=4096,N=128,K=512) -> bf16 (B,4096,128)
  p = GemmP{};
  p.A = xbT; p.aS = 4096L * 512; p.lda = 512;
  p.Bt = wqk; p.bS = 0; p.ldb = 512;
  p.C = QKT; p.cSbytes = 4096L * 128 * 2; p.ldc = 128;
  p.K = 512; p.biasN = bqk;
  gemm_k<128, 64, 2, 0><<<dim3(32, 2, 4), 256, 0, stream>>>(p);

  // V = wpv * x + bpv  (M=512,N=4096,K=512) -> bf16 (B,512,4096)  [XCD remap]
  p = GemmP{};
  p.A = wpvb; p.aS = 0; p.lda = 512;
  p.Bt = xbT; p.bS = 4096L * 512; p.ldb = 512;
  p.C = V; p.cSbytes = 512L * 4096 * 2; p.ldc = 4096;
  p.K = 512; p.biasM = bpv; p.remap = 1;
  gemm_k<128, 128, 1, 0><<<dim3(512, 1, 1), 256, 0, stream>>>(p);

  flash_pos<<<dim3(512, 1, 1), 512, 57856, stream>>>(QKT, V, x, gpos, Pb, PTb, rws);

  // Gram: G = P*P^T  (M=N=512,K=4096) -> bf16
  p = GemmP{};
  p.A = Pb; p.aS = 512L * 4096; p.lda = 4096;
  p.Bt = Pb; p.bS = 512L * 4096; p.ldb = 4096;
  p.C = G; p.cSbytes = 512L * 512 * 2; p.ldc = 512;
  p.K = 4096;
  gemm_k<64, 64, 0, 0><<<dim3(8, 8, 4), 256, 0, stream>>>(p);

  uv_kernel<<<dim3(2, 2, 4), 256, 0, stream>>>(wcq, wck, rws, uws, vws);

  // M1 = Wcq * G (G symmetric)  -> bf16
  p = GemmP{};
  p.A = wcqb; p.aS = 0; p.lda = 512;
  p.Bt = G; p.bS = 512L * 512; p.ldb = 512;
  p.C = M1; p.cSbytes = 512L * 512 * 2; p.ldc = 512;
  p.K = 512;
  gemm_k<64, 64, 0, 0><<<dim3(8, 8, 4), 256, 0, stream>>>(p);

  // L = M1 * Wck^T + rank1 bias terms -> f32
  p = GemmP{};
  p.A = M1; p.aS = 512L * 512; p.lda = 512;
  p.Bt = wckb; p.bS = 0; p.ldb = 512;
  p.C = Lws; p.cSbytes = 512L * 512 * 4; p.ldc = 512;
  p.K = 512;
  p.e_bq = bcq; p.e_v = vws; p.vS = 512; p.e_u = uws; p.uS = 512; p.e_bk = bck; p.e_nn = 4096.f;
  gemm_k<64, 64, 0, 2><<<dim3(8, 8, 4), 256, 0, stream>>>(p);

  softmax_chan<<<dim3(128, 1, 4), 256, 0, stream>>>(Lws, bcv, Ab, Abv);

  // B2 = A * Wcv  -> bf16
  p = GemmP{};
  p.A = Ab; p.aS = 512L * 512; p.lda = 512;
  p.Bt = wcvT; p.bS = 0; p.ldb = 512;
  p.C = B2; p.cSbytes = 512L * 512 * 2; p.ldc = 512;
  p.K = 512;
  gemm_k<64, 64, 0, 0><<<dim3(8, 8, 4), 256, 0, stream>>>(p);

  // out = gchan*(B2*P + Abv) + pos_out  (M=512,N=4096,K=512) f32  [XCD remap]
  p = GemmP{};
  p.A = B2; p.aS = 512L * 512; p.lda = 512;
  p.Bt = PTb; p.bS = 4096L * 512; p.ldb = 512;
  p.C = out; p.cSbytes = 512L * 4096 * 4; p.ldc = 4096;
  p.K = 512;
  p.gchan = gch; p.Abv = Abv; p.abvS = 512; p.Pres = Pb; p.presS = 512L * 4096;
  p.remap = 1;
  gemm_k<128, 128, 0, 3><<<dim3(512, 1, 1), 256, 0, stream>>>(p);
}

// Round 12
// 267.265 us; speedup vs baseline: 1.5350x; 1.5350x over previous
//
#include <hip/hip_runtime.h>
#include <hip/hip_bf16.h>
#include <math.h>

typedef __bf16 bf16;
typedef __attribute__((ext_vector_type(8))) __bf16 bf16x8;
typedef __attribute__((ext_vector_type(4))) __bf16 bf16x4;
typedef __attribute__((ext_vector_type(4))) float f32x4;

#define DEVI static __device__ __forceinline__

// byte offset of 16B chunk within a 128B LDS row, XOR-swizzled
DEVI int swzb(int row, int ch) { return ((ch ^ (row & 7)) << 4); }

// async global->LDS 16B: per-lane global src, wave-uniform LDS base (+lane*16 by HW)
DEVI void gl_lds16(const void* g, void* l) {
  __builtin_amdgcn_global_load_lds(
      (const __attribute__((address_space(1))) unsigned int*)g,
      (__attribute__((address_space(3))) unsigned int*)l, 16, 0, 0);
}

template<int N> DEVI void wait_vm() {
  if constexpr (N == 0) asm volatile("s_waitcnt vmcnt(0)" ::: "memory");
  else if constexpr (N == 4) asm volatile("s_waitcnt vmcnt(4)" ::: "memory");
  else if constexpr (N == 6) asm volatile("s_waitcnt vmcnt(6)" ::: "memory");
  else if constexpr (N == 8) asm volatile("s_waitcnt vmcnt(8)" ::: "memory");
}
DEVI void sbar() {
  __builtin_amdgcn_sched_barrier(0);
  __builtin_amdgcn_s_barrier();
  __builtin_amdgcn_sched_barrier(0);
}

// ---------------------------------------------------------------------------
// prep: weights -> bf16 (wqk = concat(wpq,wpk); wcvT = wcv transposed), bqk
// ---------------------------------------------------------------------------
__global__ __launch_bounds__(256) void prep_weights(
    const float* __restrict__ wpq, const float* __restrict__ wpk,
    const float* __restrict__ wpv, const float* __restrict__ wcq,
    const float* __restrict__ wck, const float* __restrict__ wcv,
    const float* __restrict__ bpq, const float* __restrict__ bpk,
    bf16* __restrict__ wqk, bf16* __restrict__ wpvb, bf16* __restrict__ wcqb,
    bf16* __restrict__ wckb, bf16* __restrict__ wcvT, float* __restrict__ bqk)
{
  int i = blockIdx.x * 256 + threadIdx.x;
  switch (blockIdx.y) {
    case 0: if (i < 64*512)  wqk[i]          = (bf16)wpq[i]; break;
    case 1: if (i < 64*512)  wqk[64*512 + i] = (bf16)wpk[i]; break;
    case 2: if (i < 512*512) wpvb[i] = (bf16)wpv[i]; break;
    case 3: if (i < 512*512) wcqb[i] = (bf16)wcq[i]; break;
    case 4: if (i < 512*512) wckb[i] = (bf16)wck[i]; break;
    case 5: if (i < 512*512) { int t = i >> 9, j = i & 511; wcvT[i] = (bf16)wcv[j*512 + t]; } break;
    case 6: if (i < 64) bqk[i] = bpq[i]; else if (i < 128) bqk[i] = bpk[i - 64]; break;
  }
}

// ---------------------------------------------------------------------------
// x (B,512,4096) fp32 -> xbT (B,4096,512) bf16
// ---------------------------------------------------------------------------
__global__ __launch_bounds__(256) void transpose_x(const float* __restrict__ x, bf16* __restrict__ xbT)
{
  __shared__ float t[32][33];
  int b = blockIdx.z, n0 = blockIdx.x * 32, c0 = blockIdx.y * 32;
  int tx = threadIdx.x & 31, ty = threadIdx.x >> 5;
#pragma unroll
  for (int i = 0; i < 4; ++i)
    t[ty + 8*i][tx] = x[((size_t)b*512 + c0 + ty + 8*i)*4096 + n0 + tx];
  __syncthreads();
#pragma unroll
  for (int i = 0; i < 4; ++i)
    xbT[((size_t)b*4096 + n0 + ty + 8*i)*512 + c0 + tx] = (bf16)t[tx][ty + 8*i];
}

// ---------------------------------------------------------------------------
// generic bf16 MFMA GEMM. C[m,n] = sum_k A[m,k]*Bt[n,k]  (+bias/epilogues)
// (BM+BN)<=192: triple-buffered, raw barrier + counted vmcnt. Else 2-buf sync.
// BIAS: 0 none, 1 +biasM[m], 2 +biasN[n]
// EPI : 0 bf16 store, 1 f32 store, 2 f32 + rank1 bias terms (L), 3 final out
// remap=1: flat grid (512), batch pinned to XCD pair (assumes phys%8 = XCD)
// ---------------------------------------------------------------------------
struct GemmP {
  const bf16* A; const bf16* Bt; void* C;
  long aS, bS;       // batch strides (elements)
  long cSbytes;      // batch stride of C in bytes
  int lda, ldb, ldc, K;
  int remap;
  const float* biasM; const float* biasN;
  const float* e_bq; const float* e_v; const float* e_u; const float* e_bk; float e_nn;
  long vS, uS;
  const float* gchan; const float* Abv; const bf16* Pres; long abvS, presS;
};

template<int BM, int BN, int BIAS, int EPI>
__global__ __launch_bounds__(256) void gemm_k(GemmP p)
{
  constexpr int QF = BM / 32;
  constexpr int CF = BN / 32;
  constexpr int NBUF = (BM + BN <= 192) ? 3 : 2;
  constexpr int LOADS = (BM + BN) / 32;   // gl_lds per wave per stage
  __shared__ __align__(16) char sa[NBUF][BM * 128];
  __shared__ __align__(16) char sb[NBUF][BN * 128];
  const int tid = threadIdx.x, lane = tid & 63, w = tid >> 6;
  const int g = lane >> 4, l15 = lane & 15;
  int bx = blockIdx.x, by = blockIdx.y, bz = blockIdx.z;
  if (p.remap) {  // grid (4,32,4) flattened to 512; batch -> XCD pair
    int ph = blockIdx.x;
    bz = (ph & 7) >> 1;
    int idx = ((ph & 1) << 6) | (ph >> 3);  // [0,128)
    bx = idx & 3; by = idx >> 2;
  }
  const int bm = bx * BM, bn = by * BN;
  const bf16* A  = p.A  + (size_t)bz * p.aS;
  const bf16* Bt = p.Bt + (size_t)bz * p.bS;
  char* Cb = (char*)p.C + (size_t)bz * p.cSbytes;
  const int wm = (w & 1) * (BM / 2), wn = (w >> 1) * (BN / 2);
  const int srow = tid >> 3, sch = tid & 7;

  f32x4 acc[QF][CF];
#pragma unroll
  for (int i = 0; i < QF; ++i)
#pragma unroll
    for (int j = 0; j < CF; ++j) acc[i][j] = f32x4{0.f, 0.f, 0.f, 0.f};

  auto stage = [&](int k0, int bi) {
#pragma unroll
    for (int it = 0; it < BM / 32; ++it) {
      int r = it * 32 + srow;
      gl_lds16(A + (size_t)(bm + r) * p.lda + k0 + ((sch ^ (r & 7)) * 8),
               sa[bi] + (it * 32 + w * 8) * 128);
    }
#pragma unroll
    for (int it = 0; it < BN / 32; ++it) {
      int r = it * 32 + srow;
      gl_lds16(Bt + (size_t)(bn + r) * p.ldb + k0 + ((sch ^ (r & 7)) * 8),
               sb[bi] + (it * 32 + w * 8) * 128);
    }
  };
  auto compute = [&](int bi) {
#pragma unroll
    for (int kc = 0; kc < 2; ++kc) {
      bf16x8 af[QF], bfr[CF];
#pragma unroll
      for (int qf = 0; qf < QF; ++qf) {
        int row = wm + 16 * qf + l15;
        af[qf] = *(const bf16x8*)(sa[bi] + row * 128 + swzb(row, g + 4 * kc));
      }
#pragma unroll
      for (int cf = 0; cf < CF; ++cf) {
        int row = wn + 16 * cf + l15;
        bfr[cf] = *(const bf16x8*)(sb[bi] + row * 128 + swzb(row, g + 4 * kc));
      }
      __builtin_amdgcn_s_setprio(1);
#pragma unroll
      for (int qf = 0; qf < QF; ++qf)
#pragma unroll
        for (int cf = 0; cf < CF; ++cf)
          acc[qf][cf] = __builtin_amdgcn_mfma_f32_16x16x32_bf16(af[qf], bfr[cf], acc[qf][cf], 0, 0, 0);
      __builtin_amdgcn_s_setprio(0);
    }
  };

  const int nk = p.K >> 6;
  if constexpr (NBUF == 3) {
    stage(0, 0);
    if (nk > 1) { stage(64, 1); wait_vm<LOADS>(); } else wait_vm<0>();
    sbar();
    int bi = 0;
    for (int t = 0; t < nk; ++t) {
      int b2 = bi + 2; if (b2 >= 3) b2 -= 3;
      if (t + 2 < nk) stage((t + 2) << 6, b2);
      compute(bi);
      if (t + 1 < nk) {
        if (t + 2 < nk) wait_vm<LOADS>(); else wait_vm<0>();
        sbar();
      }
      if (++bi == 3) bi = 0;
    }
  } else {
    stage(0, 0);
    __syncthreads();
    for (int t = 0; t < nk; ++t) {
      const int cur = t & 1;
      if (t + 1 < nk) stage((t + 1) << 6, cur ^ 1);
      compute(cur);
      __syncthreads();
    }
  }

  // epilogue
  float gc = 0.f;
  const float* AbvB = nullptr; const bf16* PresB = nullptr;
  const float* eV = nullptr; const float* eU = nullptr;
  if (EPI == 3) { gc = p.gchan[0]; AbvB = p.Abv + (size_t)bz * p.abvS; PresB = p.Pres + (size_t)bz * p.presS; }
  if (EPI == 2) { eV = p.e_v + (size_t)bz * p.vS; eU = p.e_u + (size_t)bz * p.uS; }

#pragma unroll
  for (int qf = 0; qf < QF; ++qf)
#pragma unroll
    for (int cf = 0; cf < CF; ++cf)
#pragma unroll
      for (int r = 0; r < 4; ++r) {
        int m = bm + wm + 16 * qf + 4 * g + r;
        int n = bn + wn + 16 * cf + l15;
        float v = acc[qf][cf][r];
        if (BIAS == 1) v += p.biasM[m];
        if (BIAS == 2) v += p.biasN[n];
        size_t idx = (size_t)m * p.ldc + n;
        if (EPI == 0) ((bf16*)Cb)[idx] = (bf16)v;
        else if (EPI == 1) ((float*)Cb)[idx] = v;
        else if (EPI == 2) {
          v += p.e_bq[m] * eV[n] + eU[m] * p.e_bk[n] + p.e_nn * p.e_bq[m] * p.e_bk[n];
          ((float*)Cb)[idx] = v;
        } else {
          v = gc * (v + AbvB[m]) + (float)PresB[idx];
          ((float*)Cb)[idx] = v;
        }
      }
}

// ---------------------------------------------------------------------------
// flash position attention (r7 champion, verbatim — no atomics).
//  - c-split: 64q x 256c per block, grid 512 = 2 blocks/CU
//  - K dbuf gl_lds; V staged via gl_lds issued after barrier2, retired at
//    barrier1 (vmcnt(1): K stays airborne); 2 barriers/iter
// LDS: K0@0 K1@8K V@16K P@48K lsum@56K; epilogue Och reuse [0,34816)
// ---------------------------------------------------------------------------
__global__ __launch_bounds__(512, 4) void flash_pos(
    const bf16* __restrict__ QKT, const bf16* __restrict__ Vv,
    const float* __restrict__ x, const float* __restrict__ gpos,
    bf16* __restrict__ Pb, bf16* __restrict__ PTb)
{
  extern __shared__ char sm[];
  char* Vlds = sm + 16384;
  char* Plds = sm + 49152;
  float* Och  = (float*)sm;
  float* lsum = (float*)(sm + 57344);

  const int tid = threadIdx.x, lane = tid & 63, w = tid >> 6;
  const int g = lane >> 4, l15 = lane & 15;
  const int wq = w & 3;                  // q-row group (rows 16wq..16wq+15)
  const int wh = w >> 2;                 // kv col half (cols 32wh..32wh+31)
  const int phys = blockIdx.x;
  const int b  = (phys & 7) >> 1;
  const int ch = phys & 1;
  const int q0 = (phys >> 3) << 6;
  const int c0 = ch << 8;

  const bf16* QKTb = QKT + (size_t)b * 4096 * 128;
  const bf16* Vb   = Vv  + (size_t)b * 512 * 4096;

  const bf16* qrow = QKTb + (size_t)(q0 + 16 * wq + l15) * 128;
  bf16x8 qa0 = *(const bf16x8*)(qrow + 8 * g);
  bf16x8 qa1 = *(const bf16x8*)(qrow + 32 + 8 * g);

  f32x4 acc[4][2];
#pragma unroll
  for (int i = 0; i < 4; ++i) { acc[i][0] = f32x4{0.f,0.f,0.f,0.f}; acc[i][1] = f32x4{0.f,0.f,0.f,0.f}; }
  f32x4 l_r = f32x4{0.f, 0.f, 0.f, 0.f};

  const int srow = tid >> 3, sch = tid & 7;
  const bf16* Ksrc = QKTb + (size_t)srow * 128 + 64 + ((sch ^ (srow & 7)) * 8); // + kt*8192

  // prologue: stage K(0) + V(0)
  gl_lds16(Ksrc, sm + w * 1024);
#pragma unroll
  for (int it = 0; it < 4; ++it) {
    int r = it * 64 + srow;
    gl_lds16(Vb + (size_t)(c0 + r) * 4096 + ((sch ^ (r & 7)) * 8),
             Vlds + (it * 64 + w * 8) * 128);
  }
  asm volatile("s_waitcnt vmcnt(0)" ::: "memory");
  sbar();

  for (int t = 0; t < 64; ++t) {
    const char* Kcur = sm + ((t & 1) << 13);
    char* Knext = sm + (((t + 1) & 1) << 13);
    const int ktn = (t + 1) & 63;
    // ---- phase A: stage K(t+1); QK(t); exp; P write ----
    gl_lds16(Ksrc + (size_t)ktn * 8192, Knext + w * 1024);
    __builtin_amdgcn_sched_barrier(0);
    f32x4 s0 = f32x4{0.f,0.f,0.f,0.f}, s1 = f32x4{0.f,0.f,0.f,0.f};
    {
      const int r0 = 32 * wh + l15, r1 = r0 + 16;
      bf16x8 k00 = *(const bf16x8*)(Kcur + r0 * 128 + swzb(r0, g));
      bf16x8 k01 = *(const bf16x8*)(Kcur + r0 * 128 + swzb(r0, g + 4));
      bf16x8 k10 = *(const bf16x8*)(Kcur + r1 * 128 + swzb(r1, g));
      bf16x8 k11 = *(const bf16x8*)(Kcur + r1 * 128 + swzb(r1, g + 4));
      __builtin_amdgcn_s_setprio(1);
      s0 = __builtin_amdgcn_mfma_f32_16x16x32_bf16(qa0, k00, s0, 0, 0, 0);
      s0 = __builtin_amdgcn_mfma_f32_16x16x32_bf16(qa1, k01, s0, 0, 0, 0);
      s1 = __builtin_amdgcn_mfma_f32_16x16x32_bf16(qa0, k10, s1, 0, 0, 0);
      s1 = __builtin_amdgcn_mfma_f32_16x16x32_bf16(qa1, k11, s1, 0, 0, 0);
      __builtin_amdgcn_s_setprio(0);
    }
#pragma unroll
    for (int r = 0; r < 4; ++r) {
      float e0 = __expf(s0[r]), e1 = __expf(s1[r]);
      l_r[r] += e0 + e1;
      int row = 16 * wq + 4 * g + r;
      int ca = 32 * wh + l15, cb = ca + 16;
      *(bf16*)(Plds + row * 128 + (((ca >> 3) ^ (row & 7)) << 4) + ((ca & 7) * 2)) = (bf16)e0;
      *(bf16*)(Plds + row * 128 + (((cb >> 3) ^ (row & 7)) << 4) + ((cb & 7) * 2)) = (bf16)e1;
    }
    // barrier1: P(t) visible; V(t) landed (vmcnt(1): K(t+1) stays airborne)
    asm volatile("s_waitcnt vmcnt(1) lgkmcnt(0)" ::: "memory");
    sbar();
    // ---- phase B: PV(t) from LDS ----
    __builtin_amdgcn_s_setprio(1);
#pragma unroll
    for (int kc = 0; kc < 2; ++kc) {
      const int vra = 32 * w + l15, vrb = vra + 16;
      bf16x8 v0 = *(const bf16x8*)(Vlds + vra * 128 + swzb(vra, g + 4 * kc));
      bf16x8 v1 = *(const bf16x8*)(Vlds + vrb * 128 + swzb(vrb, g + 4 * kc));
#pragma unroll
      for (int qf = 0; qf < 4; ++qf) {
        int row = 16 * qf + l15;
        bf16x8 ap = *(const bf16x8*)(Plds + row * 128 + swzb(row, g + 4 * kc));
        acc[qf][0] = __builtin_amdgcn_mfma_f32_16x16x32_bf16(ap, v0, acc[qf][0], 0, 0, 0);
        acc[qf][1] = __builtin_amdgcn_mfma_f32_16x16x32_bf16(ap, v1, acc[qf][1], 0, 0, 0);
      }
    }
    __builtin_amdgcn_s_setprio(0);
    // barrier2: K(t+1) landed, all PV LDS reads done -> V/P safe to overwrite
    asm volatile("s_waitcnt vmcnt(0) lgkmcnt(0)" ::: "memory");
    sbar();
    // stage V(t+1) (retired at barrier1 of t+1 via vmcnt(1))
#pragma unroll
    for (int it = 0; it < 4; ++it) {
      int r = it * 64 + srow;
      gl_lds16(Vb + (size_t)(c0 + r) * 4096 + ktn * 64 + ((sch ^ (r & 7)) * 8),
               Vlds + (it * 64 + w * 8) * 128);
    }
  }
  // drain wrap prefetch before LDS reuse as Och
  asm volatile("s_waitcnt vmcnt(0) lgkmcnt(0)" ::: "memory");
  sbar();

  // reduce l over the 16 lanes of each group (covers this wave's 32 cols)
#pragma unroll
  for (int off = 1; off < 16; off <<= 1) {
#pragma unroll
    for (int r = 0; r < 4; ++r) l_r[r] += __shfl_xor(l_r[r], off);
  }
  if (l15 == 0)
#pragma unroll
    for (int r = 0; r < 4; ++r) lsum[wh * 64 + 16 * wq + 4 * g + r] = l_r[r];
  __syncthreads();

  const float gp = gpos[0];
  for (int j = 0; j < 2; ++j) { // c chunks of 128 within this block's 256
    if ((w >> 2) == j) {
#pragma unroll
      for (int qf = 0; qf < 4; ++qf) {
        float inv[4];
#pragma unroll
        for (int r = 0; r < 4; ++r) {
          int qi = 16 * qf + 4 * g + r;
          inv[r] = gp / (lsum[qi] + lsum[64 + qi]);
        }
#pragma unroll
        for (int cf = 0; cf < 2; ++cf) {
          int cl = 32 * (w & 3) + 16 * cf + l15;
#pragma unroll
          for (int r = 0; r < 4; ++r)
            Och[cl * 68 + 16 * qf + 4 * g + r] = acc[qf][cf][r] * inv[r];
        }
      }
    }
    __syncthreads();
    { // pass1: residual add + Pb write (rows c)
      int cl = tid >> 2, qs = (tid & 3) * 16;
      int cg = c0 + 128 * j + cl;
      const float* xr = x + ((size_t)b * 512 + cg) * 4096 + q0 + qs;
      float* och = Och + cl * 68 + qs;
      float tmp[16];
#pragma unroll
      for (int i = 0; i < 16; ++i) { tmp[i] = och[i] + xr[i]; och[i] = tmp[i]; }
      bf16x8 o0, o1;
#pragma unroll
      for (int i = 0; i < 8; ++i) { o0[i] = (bf16)tmp[i]; o1[i] = (bf16)tmp[i + 8]; }
      bf16* pr = Pb + ((size_t)b * 512 + cg) * 4096 + q0 + qs;
      *(bf16x8*)pr = o0; *(bf16x8*)(pr + 8) = o1;
    }
    __syncthreads();
    { // pass2: PT write (rows q)
      int q = tid >> 3, cs = (tid & 7) * 16;
      float tmp[16];
#pragma unroll
      for (int i = 0; i < 16; ++i) tmp[i] = Och[(cs + i) * 68 + q];
      bf16x8 o0, o1;
#pragma unroll
      for (int i = 0; i < 8; ++i) { o0[i] = (bf16)tmp[i]; o1[i] = (bf16)tmp[i + 8]; }
      bf16* pt = PTb + ((size_t)b * 4096 + q0 + q) * 512 + c0 + 128 * j + cs;
      *(bf16x8*)pt = o0; *(bf16x8*)(pt + 8) = o1;
    }
    __syncthreads();
  }
}

// ---------------------------------------------------------------------------
// r[b][c] = sum_n Pb[b][c][n]
// ---------------------------------------------------------------------------
__global__ __launch_bounds__(256) void row_sum(const bf16* __restrict__ Pb, float* __restrict__ r)
{
  int wid = blockIdx.x * 4 + (threadIdx.x >> 6);
  int lane = threadIdx.x & 63;
  const bf16* row = Pb + (size_t)wid * 4096;
  float s = 0.f;
#pragma unroll
  for (int i = 0; i < 8; ++i) {
    bf16x8 v = ((const bf16x8*)row)[lane + 64 * i];
#pragma unroll
    for (int j = 0; j < 8; ++j) s += (float)v[j];
  }
#pragma unroll
  for (int off = 1; off < 64; off <<= 1) s += __shfl_xor(s, off);
  if (lane == 0) r[wid] = s;
}

// u = Wcq*r, v = Wck*r  (fp32)
__global__ __launch_bounds__(256) void uv_kernel(
    const float* __restrict__ wcq, const float* __restrict__ wck,
    const float* __restrict__ r, float* __restrict__ u, float* __restrict__ v)
{
  int b = blockIdx.z;
  int i = blockIdx.x * 256 + threadIdx.x;
  const float* rb = r + b * 512;
  const float* wrow = (blockIdx.y ? wck : wcq) + (size_t)i * 512;
  float s = 0.f;
  for (int t = 0; t < 512; ++t) s += wrow[t] * rb[t];
  (blockIdx.y ? v : u)[b * 512 + i] = s;
}

// softmax over rows of L (512 wide) -> Ab bf16 ; Abv[i] = sum_j A[i,j]*bcv[j]
__global__ __launch_bounds__(256) void softmax_chan(
    const float* __restrict__ L, const float* __restrict__ bcv,
    bf16* __restrict__ Ab, float* __restrict__ Abv)
{
  int b = blockIdx.z;
  int i = blockIdx.x * 4 + (threadIdx.x >> 6);
  int lane = threadIdx.x & 63;
  const float* row = L + ((size_t)b * 512 + i) * 512;
  f32x4 v0 = ((const f32x4*)row)[lane];
  f32x4 v1 = ((const f32x4*)row)[lane + 64];
  float mx = fmaxf(fmaxf(fmaxf(v0[0], v0[1]), fmaxf(v0[2], v0[3])),
                   fmaxf(fmaxf(v1[0], v1[1]), fmaxf(v1[2], v1[3])));
#pragma unroll
  for (int off = 1; off < 64; off <<= 1) mx = fmaxf(mx, __shfl_xor(mx, off));
  float e[8]; float s = 0.f;
#pragma unroll
  for (int k = 0; k < 4; ++k) { e[k] = __expf(v0[k] - mx); s += e[k]; }
#pragma unroll
  for (int k = 0; k < 4; ++k) { e[4 + k] = __expf(v1[k] - mx); s += e[4 + k]; }
#pragma unroll
  for (int off = 1; off < 64; off <<= 1) s += __shfl_xor(s, off);
  float inv = 1.f / s;
  bf16x4 a0, a1;
  const f32x4 bv0 = ((const f32x4*)bcv)[lane];
  const f32x4 bv1 = ((const f32x4*)bcv)[lane + 64];
  float pb = 0.f;
#pragma unroll
  for (int k = 0; k < 4; ++k) {
    float p0 = e[k] * inv, p1 = e[4 + k] * inv;
    a0[k] = (bf16)p0; a1[k] = (bf16)p1;
    pb += p0 * bv0[k] + p1 * bv1[k];
  }
  bf16* arow = Ab + ((size_t)b * 512 + i) * 512;
  *(bf16x4*)(arow + 4 * lane) = a0;
  *(bf16x4*)(arow + 256 + 4 * lane) = a1;
#pragma unroll
  for (int off = 1; off < 64; off <<= 1) pb += __shfl_xor(pb, off);
  if (lane == 0) Abv[b * 512 + i] = pb;
}

// ---------------------------------------------------------------------------
extern "C" void kernel_launch(void* const* d_in, const int* in_sizes, int n_in,
                              void* d_out, int out_size, void* d_ws, size_t ws_size,
                              hipStream_t stream)
{
  const float* x    = (const float*)d_in[0];
  const float* wpq  = (const float*)d_in[1];
  const float* bpq  = (const float*)d_in[2];
  const float* wpk  = (const float*)d_in[3];
  const float* bpk  = (const float*)d_in[4];
  const float* wpv  = (const float*)d_in[5];
  const float* bpv  = (const float*)d_in[6];
  const float* wcq  = (const float*)d_in[7];
  const float* bcq  = (const float*)d_in[8];
  const float* wck  = (const float*)d_in[9];
  const float* bck  = (const float*)d_in[10];
  const float* wcv  = (const float*)d_in[11];
  const float* bcv  = (const float*)d_in[12];
  const float* gpos = (const float*)d_in[13];
  const float* gch  = (const float*)d_in[14];
  float* out = (float*)d_out;

  char* ws = (char*)d_ws;
  size_t off = 0;
  auto alloc = [&](size_t bytes) -> char* {
    char* p = ws + off; off = (off + bytes + 255) & ~(size_t)255; return p;
  };
  bf16*  xbT  = (bf16*)alloc(4UL * 4096 * 512 * 2);
  bf16*  QKT  = (bf16*)alloc(4UL * 4096 * 128 * 2);
  bf16*  V    = (bf16*)alloc(4UL * 512 * 4096 * 2);
  bf16*  Pb   = (bf16*)alloc(4UL * 512 * 4096 * 2);
  bf16*  PTb  = (bf16*)alloc(4UL * 4096 * 512 * 2);
  bf16*  G    = (bf16*)alloc(4UL * 512 * 512 * 2);
  bf16*  M1   = (bf16*)alloc(4UL * 512 * 512 * 2);
  float* Lws  = (float*)alloc(4UL * 512 * 512 * 4);
  bf16*  Ab   = (bf16*)alloc(4UL * 512 * 512 * 2);
  bf16*  B2   = (bf16*)alloc(4UL * 512 * 512 * 2);
  bf16*  wqk  = (bf16*)alloc(128UL * 512 * 2);
  bf16*  wpvb = (bf16*)alloc(512UL * 512 * 2);
  bf16*  wcqb = (bf16*)alloc(512UL * 512 * 2);
  bf16*  wckb = (bf16*)alloc(512UL * 512 * 2);
  bf16*  wcvT = (bf16*)alloc(512UL * 512 * 2);
  float* bqk  = (float*)alloc(128 * 4);
  float* rws  = (float*)alloc(4UL * 512 * 4);
  float* uws  = (float*)alloc(4UL * 512 * 4);
  float* vws  = (float*)alloc(4UL * 512 * 4);
  float* Abv  = (float*)alloc(4UL * 512 * 4);
  if (off > ws_size) return;  // workspace too small: bail (bench will flag)

  prep_weights<<<dim3(1024, 7, 1), 256, 0, stream>>>(wpq, wpk, wpv, wcq, wck, wcv,
                                                     bpq, bpk, wqk, wpvb, wcqb, wckb, wcvT, bqk);
  transpose_x<<<dim3(128, 16, 4), 256, 0, stream>>>(x, xbT);

  GemmP p{};
  // QKT = xbT * wqk^T + bqk   (M=4096,N=128,K=512) -> bf16 (B,4096,128)
  p = GemmP{};
  p.A = xbT; p.aS = 4096L * 512; p.lda = 512;
  p.Bt = wqk; p.bS = 0; p.ldb = 512;
  p.C = QKT; p.cSbytes = 4096L * 128 * 2; p.ldc = 128;
  p.K = 512; p.biasN = bqk;
  gemm_k<128, 64, 2, 0><<<dim3(32, 2, 4), 256, 0, stream>>>(p);

  // V = wpv * x + bpv  (M=512,N=4096,K=512) -> bf16 (B,512,4096)  [XCD remap]
  p = GemmP{};
  p.A = wpvb; p.aS = 0; p.lda = 512;
  p.Bt = xbT; p.bS = 4096L * 512; p.ldb = 512;
  p.C = V; p.cSbytes = 512L * 4096 * 2; p.ldc = 4096;
  p.K = 512; p.biasM = bpv; p.remap = 1;
  gemm_k<128, 128, 1, 0><<<dim3(512, 1, 1), 256, 0, stream>>>(p);

  flash_pos<<<dim3(512, 1, 1), 512, 57856, stream>>>(QKT, V, x, gpos, Pb, PTb);

  // Gram: G = P*P^T  (M=N=512,K=4096) -> bf16
  p = GemmP{};
  p.A = Pb; p.aS = 512L * 4096; p.lda = 4096;
  p.Bt = Pb; p.bS = 512L * 4096; p.ldb = 4096;
  p.C = G; p.cSbytes = 512L * 512 * 2; p.ldc = 512;
  p.K = 4096;
  gemm_k<64, 64, 0, 0><<<dim3(8, 8, 4), 256, 0, stream>>>(p);

  row_sum<<<dim3(512, 1, 1), 256, 0, stream>>>(Pb, rws);
  uv_kernel<<<dim3(2, 2, 4), 256, 0, stream>>>(wcq, wck, rws, uws, vws);

  // M1 = Wcq * G (G symmetric)  -> bf16
  p = GemmP{};
  p.A = wcqb; p.aS = 0; p.lda = 512;
  p.Bt = G; p.bS = 512L * 512; p.ldb = 512;
  p.C = M1; p.cSbytes = 512L * 512 * 2; p.ldc = 512;
  p.K = 512;
  gemm_k<64, 64, 0, 0><<<dim3(8, 8, 4), 256, 0, stream>>>(p);

  // L = M1 * Wck^T + rank1 bias terms -> f32
  p = GemmP{};
  p.A = M1; p.aS = 512L * 512; p.lda = 512;
  p.Bt = wckb; p.bS = 0; p.ldb = 512;
  p.C = Lws; p.cSbytes = 512L * 512 * 4; p.ldc = 512;
  p.K = 512;
  p.e_bq = bcq; p.e_v = vws; p.vS = 512; p.e_u = uws; p.uS = 512; p.e_bk = bck; p.e_nn = 4096.f;
  gemm_k<64, 64, 0, 2><<<dim3(8, 8, 4), 256, 0, stream>>>(p);

  softmax_chan<<<dim3(128, 1, 4), 256, 0, stream>>>(Lws, bcv, Ab, Abv);

  // B2 = A * Wcv  -> bf16
  p = GemmP{};
  p.A = Ab; p.aS = 512L * 512; p.lda = 512;
  p.Bt = wcvT; p.bS = 0; p.ldb = 512;
  p.C = B2; p.cSbytes = 512L * 512 * 2; p.ldc = 512;
  p.K = 512;
  gemm_k<64, 64, 0, 0><<<dim3(8, 8, 4), 256, 0, stream>>>(p);

  // out = gchan*(B2*P + Abv) + pos_out  (M=512,N=4096,K=512) f32  [XCD remap]
  p = GemmP{};
  p.A = B2; p.aS = 512L * 512; p.lda = 512;
  p.Bt = PTb; p.bS = 4096L * 512; p.ldb = 512;
  p.C = out; p.cSbytes = 512L * 4096 * 4; p.ldc = 4096;
  p.K = 512;
  p.gchan = gch; p.Abv = Abv; p.abvS = 512; p.Pres = Pb; p.presS = 512L * 4096;
  p.remap = 1;
  gemm_k<128, 128, 0, 3><<<dim3(512, 1, 1), 256, 0, stream>>>(p);
}